// Round 13
// baseline (210.637 us; speedup 1.0000x reference)
//
#include <hip/hip_runtime.h>
#include <hip/hip_bf16.h>
#include <math.h>

// Problem: CausalSelfAttention  B=4 T=2048 D=1024 H=16 HD=64
// d_in: fp32 x[4,2048,1024], Wq,Wk,Wv,Wp[1024,1024], bp[1024]; d_out: fp32 y.
// Pipeline: cvt(fp32->bf16 into ws) -> qkv -> attn -> proj.
// V stored TRANSPOSED [B,H,HD,T]. attn v11 = v10 with QBLK=32 per wave
// (128 q-rows/block): two 16-row q-strips share each staged K/V tile ->
// 2x MFMA per LDS read, half the stages/barriers per q-row.

#define B_  4
#define T_  2048
#define D_  1024
#define H_  16
#define HD_ 64
#define M_  (B_ * T_)   // 8192 rows

typedef short bf16x8 __attribute__((ext_vector_type(8)));
typedef float f32x4  __attribute__((ext_vector_type(4)));

__device__ __forceinline__ f32x4 mfma16(bf16x8 a, bf16x8 b, f32x4 c) {
    return __builtin_amdgcn_mfma_f32_16x16x32_bf16(a, b, c, 0, 0, 0);
}

__device__ __forceinline__ void gl_lds16(const unsigned short* g, unsigned short* l) {
    __builtin_amdgcn_global_load_lds(
        (const __attribute__((address_space(1))) void*)g,
        (__attribute__((address_space(3))) void*)l, 16, 0, 0);
}

__device__ __forceinline__ unsigned short f2bf(float f) {
    union { __hip_bfloat16 h; unsigned short u; } cv;
    cv.h = __float2bfloat16(f);
    return cv.u;
}
__device__ __forceinline__ float bf2f(unsigned short u) {
    return __uint_as_float(((unsigned)u) << 16);
}
__device__ __forceinline__ float exp2_fast(float x) {
    return __builtin_amdgcn_exp2f(x);   // v_exp_f32: 2^x
}

struct su4 { unsigned short x, y, z, w; };

// ---------------------------------------------------------------------------
__global__ __launch_bounds__(256)
void cvt_kernel(const float* __restrict__ in, unsigned short* __restrict__ out) {
    const int i = blockIdx.x * 256 + threadIdx.x;
    const float4 v = ((const float4*)in)[i];
    su4 o;
    o.x = f2bf(v.x); o.y = f2bf(v.y); o.z = f2bf(v.z); o.w = f2bf(v.w);
    ((su4*)out)[i] = o;
}

__global__ __launch_bounds__(256)
void cvtw_kernel(const float* __restrict__ w0, const float* __restrict__ w1,
                 const float* __restrict__ w2, const float* __restrict__ w3,
                 unsigned short* __restrict__ o0, unsigned short* __restrict__ o1,
                 unsigned short* __restrict__ o2, unsigned short* __restrict__ o3) {
    const int y = blockIdx.y;
    const float* in       = (y == 0) ? w0 : (y == 1) ? w1 : (y == 2) ? w2 : w3;
    unsigned short* out   = (y == 0) ? o0 : (y == 1) ? o1 : (y == 2) ? o2 : o3;
    const int i = blockIdx.x * 256 + threadIdx.x;
    const float4 v = ((const float4*)in)[i];
    su4 o;
    o.x = f2bf(v.x); o.y = f2bf(v.y); o.z = f2bf(v.z); o.w = f2bf(v.w);
    ((su4*)out)[i] = o;
}

// ---------------------------------------------------------------------------
// Fused QKV GEMM: C = X @ W^T.  Q,K scattered to [B,H,T,HD]; V to [B,H,HD,T]
// via operand-swapped MFMA (acc holds C^T for the V section).
// ---------------------------------------------------------------------------
__global__ __launch_bounds__(256, 2)
void qkv_kernel(const unsigned short* __restrict__ X,
                const unsigned short* __restrict__ Wq,
                const unsigned short* __restrict__ Wk,
                const unsigned short* __restrict__ Wv,
                unsigned short* __restrict__ Qo,
                unsigned short* __restrict__ Ko,
                unsigned short* __restrict__ Vo)
{
    __shared__ unsigned short As[128 * 64];
    __shared__ unsigned short Bs[128 * 64];

    const int m0 = blockIdx.x * 128;
    const int by = blockIdx.y;
    const unsigned short* W = (by < 8) ? Wq : (by < 16) ? Wk : Wv;
    unsigned short*       O = (by < 8) ? Qo : (by < 16) ? Ko : Vo;
    const int n0   = (by & 7) * 128;
    const bool vsec = (by >= 16);
    const int tid  = threadIdx.x;
    const int lane = tid & 63;
    const int wv   = tid >> 6;
    const int wr   = (wv >> 1) * 64;
    const int wc   = (wv & 1) * 64;
    const int g    = lane >> 4;
    const int c    = lane & 15;

    f32x4 acc[4][4] = {};

    for (int k0 = 0; k0 < D_; k0 += 64) {
        #pragma unroll
        for (int i = 0; i < 4; ++i) {
            const int flat = i * 2048 + tid * 8;
            const int row = flat >> 6, col = flat & 63;
            gl_lds16(X + (size_t)(m0 + row) * D_ + k0 + col, As + flat);
            gl_lds16(W + (size_t)(n0 + row) * D_ + k0 + col, Bs + flat);
        }
        __syncthreads();
        #pragma unroll
        for (int kk = 0; kk < 64; kk += 32) {
            bf16x8 af[4], bg[4];
            #pragma unroll
            for (int mi = 0; mi < 4; ++mi)
                af[mi] = *(const bf16x8*)(As + (wr + mi * 16 + c) * 64 + kk + g * 8);
            #pragma unroll
            for (int ni = 0; ni < 4; ++ni)
                bg[ni] = *(const bf16x8*)(Bs + (wc + ni * 16 + c) * 64 + kk + g * 8);
            if (!vsec) {
                #pragma unroll
                for (int mi = 0; mi < 4; ++mi)
                    #pragma unroll
                    for (int ni = 0; ni < 4; ++ni)
                        acc[mi][ni] = mfma16(af[mi], bg[ni], acc[mi][ni]);
            } else {
                #pragma unroll
                for (int mi = 0; mi < 4; ++mi)
                    #pragma unroll
                    for (int ni = 0; ni < 4; ++ni)
                        acc[mi][ni] = mfma16(bg[ni], af[mi], acc[mi][ni]);
            }
        }
        __syncthreads();
    }

    if (!vsec) {
        #pragma unroll
        for (int mi = 0; mi < 4; ++mi)
            #pragma unroll
            for (int ni = 0; ni < 4; ++ni)
                #pragma unroll
                for (int r = 0; r < 4; ++r) {
                    const int m = m0 + wr + mi * 16 + g * 4 + r;
                    const int n = n0 + wc + ni * 16 + c;
                    const int b = m >> 11, t = m & (T_ - 1);
                    const int h = n >> 6,  hd = n & 63;
                    O[((size_t)((b << 4) + h) * T_ + t) * HD_ + hd] = f2bf(acc[mi][ni][r]);
                }
    } else {
        #pragma unroll
        for (int mi = 0; mi < 4; ++mi)
            #pragma unroll
            for (int ni = 0; ni < 4; ++ni)
                #pragma unroll
                for (int r = 0; r < 4; ++r) {
                    const int n = n0 + wc + ni * 16 + g * 4 + r;
                    const int m = m0 + wr + mi * 16 + c;
                    const int b = m >> 11, t = m & (T_ - 1);
                    const int h = n >> 6,  hd = n & 63;
                    O[((size_t)((b << 4) + h) * HD_ + hd) * T_ + t] = f2bf(acc[mi][ni][r]);
                }
    }
}

// ---------------------------------------------------------------------------
// P-transpose helper (verified lane math).
// ---------------------------------------------------------------------------
__device__ __forceinline__ bf16x8 ptrans(const f32x4& p0, const f32x4& p1,
                                         int lane, int g, int c) {
    unsigned int P32[2][2];
    P32[0][0] = (unsigned int)f2bf(p0[0]) | ((unsigned int)f2bf(p0[1]) << 16);
    P32[0][1] = (unsigned int)f2bf(p0[2]) | ((unsigned int)f2bf(p0[3]) << 16);
    P32[1][0] = (unsigned int)f2bf(p1[0]) | ((unsigned int)f2bf(p1[1]) << 16);
    P32[1][1] = (unsigned int)f2bf(p1[2]) | ((unsigned int)f2bf(p1[3]) << 16);
    const int sl0 = c + ((lane & 16) << 1);
    const int sl1 = sl0 + 16;
    const int q00 = __shfl((int)P32[0][0], sl0), q10 = __shfl((int)P32[1][0], sl0);
    const int q01 = __shfl((int)P32[0][1], sl0), q11 = __shfl((int)P32[1][1], sl0);
    const int q02 = __shfl((int)P32[0][0], sl1), q12 = __shfl((int)P32[1][0], sl1);
    const int q03 = __shfl((int)P32[0][1], sl1), q13 = __shfl((int)P32[1][1], sl1);
    const bool nhi = (g & 2) != 0;
    union { unsigned int u[4]; bf16x8 v; } pf;
    pf.u[0] = nhi ? q10 : q00;
    pf.u[1] = nhi ? q11 : q01;
    pf.u[2] = nhi ? q12 : q02;
    pf.u[3] = nhi ? q13 : q03;
    return pf.v;
}

// ---------------------------------------------------------------------------
// Causal flash attention v11: QBLK=32/wave (128 rows/block), double-buffered
// LDS, 3-bit XOR swizzle, setprio, defer-max per strip, LPT grid (64 x 16).
// Each staged K/V tile feeds TWO 16-row q-strips -> 2x MFMA per LDS read.
// nt = 2*qt+2 (even) -> clean 2x-unrolled pipeline.
// ---------------------------------------------------------------------------
__global__ __launch_bounds__(256, 4)
void attn_kernel(const unsigned short* __restrict__ Q,
                 const unsigned short* __restrict__ K,
                 const unsigned short* __restrict__ VT,
                 unsigned short* __restrict__ Y)
{
    __shared__ unsigned short Ks[2][4096];   // K tiles, swizzled
    __shared__ unsigned short Vs[2][4096];   // V^T tiles, swizzled

    const int bh = blockIdx.x;          // fast axis -> XCD panel residency
    const int qt = 15 - blockIdx.y;     // LPT: heaviest q-tiles first
    const unsigned short* Qp  = Q  + (size_t)bh * T_ * HD_;
    const unsigned short* Kp  = K  + (size_t)bh * T_ * HD_;
    const unsigned short* VTp = VT + (size_t)bh * HD_ * T_;
    const int b = bh >> 4, h = bh & 15;

    const int tid  = threadIdx.x;
    const int lane = tid & 63;
    const int w    = tid >> 6;
    const int g    = lane >> 4;
    const int c    = lane & 15;
    const float SC = 0.18033688011112042f;   // (1/sqrt(64)) * log2(e)

    const int qw0 = qt * 128 + w * 32;  // strip0 rows qw0+c, strip1 rows qw0+16+c
    const int qw1 = qw0 + 16;
    const int nt  = 2 * qt + 2;         // 64-key tiles (even)

    // Staging constants (two 16B segments per 8KB half-tile); 3-bit swizzle
    int srow[2], scol[2];
    #pragma unroll
    for (int i = 0; i < 2; ++i) {
        const int L = (i * 256 + tid) * 16;
        srow[i] = L >> 7;                                   // 0..63
        scol[i] = (L & 127) ^ ((srow[i] & 7) << 4);         // pre-swizzled src col (bytes)
    }

    // Q fragments for both strips, pre-scaled (log2 domain)
    bf16x8 qf0[2], qf1[2];
    #pragma unroll
    for (int dk = 0; dk < 2; ++dk) {
        bf16x8 t0 = *(const bf16x8*)(Qp + (size_t)(qw0 + c) * HD_ + dk * 32 + g * 8);
        bf16x8 t1 = *(const bf16x8*)(Qp + (size_t)(qw1 + c) * HD_ + dk * 32 + g * 8);
        #pragma unroll
        for (int j = 0; j < 8; ++j) {
            t0[j] = (short)f2bf(bf2f((unsigned short)t0[j]) * SC);
            t1[j] = (short)f2bf(bf2f((unsigned short)t1[j]) * SC);
        }
        qf0[dk] = t0;
        qf1[dk] = t1;
    }

    float m0 = -1e30f, l0 = 0.f, m1 = -1e30f, l1 = 0.f;
    f32x4 oacc0[4] = {}, oacc1[4] = {};
    const int swz = (c & 7) << 4;       // read swizzle; read rows have row&7 == c&7

    auto stage = [&](int buf, int tb) {
        #pragma unroll
        for (int i = 0; i < 2; ++i) {
            const int L = (i * 256 + tid) * 16;
            gl_lds16(Kp + (size_t)(tb + srow[i]) * HD_ + (scol[i] >> 1),
                     &Ks[buf][L >> 1]);
            gl_lds16(VTp + (size_t)srow[i] * T_ + tb + (scol[i] >> 1),
                     &Vs[buf][L >> 1]);
        }
    };

    // softmax + ptrans for one strip; s regs become P values
    auto strip_sm = [&](f32x4 (&sA)[2], f32x4 (&sB)[2], int tb, int qws, bool domask,
                        float& m_l, float& l_l, bf16x8& pfA, bf16x8& pfB, bool& skip) {
        if (domask) {
            #pragma unroll
            for (int ni = 0; ni < 2; ++ni)
                #pragma unroll
                for (int r = 0; r < 4; ++r) {
                    const int kA = tb + ni * 16 + g * 4 + r;
                    sA[ni][r] = (kA      <= qws + c) ? sA[ni][r] : -1e30f;
                    sB[ni][r] = (kA + 32 <= qws + c) ? sB[ni][r] : -1e30f;
                }
        }
        float pmax = sA[0][0];
        #pragma unroll
        for (int ni = 0; ni < 2; ++ni)
            #pragma unroll
            for (int r = 0; r < 4; ++r) {
                pmax = fmaxf(pmax, sA[ni][r]);
                pmax = fmaxf(pmax, sB[ni][r]);
            }
        pmax = fmaxf(pmax, __shfl_xor(pmax, 16));
        pmax = fmaxf(pmax, __shfl_xor(pmax, 32));

        skip = __all(pmax - m_l <= 8.0f);
        float al = 1.f;
        if (!skip) {
            const float mn = fmaxf(m_l, pmax);
            al = exp2_fast(m_l - mn);
            m_l = mn;
        }
        float rs = 0.f;
        #pragma unroll
        for (int ni = 0; ni < 2; ++ni)
            #pragma unroll
            for (int r = 0; r < 4; ++r) {
                const float eA = exp2_fast(sA[ni][r] - m_l);
                const float eB = exp2_fast(sB[ni][r] - m_l);
                sA[ni][r] = eA; sB[ni][r] = eB;
                rs += eA + eB;
            }
        rs += __shfl_xor(rs, 16);
        rs += __shfl_xor(rs, 32);
        l_l = l_l * al + rs;
        pfA = ptrans(sA[0], sA[1], lane, g, c);
        pfB = ptrans(sB[0], sB[1], lane, g, c);
        return al;
    };

    auto compute = [&](const unsigned short* Kbuf, const unsigned short* Vbuf, int tb) {
        const char* Kb = (const char*)Kbuf;
        const char* Vb = (const char*)Vbuf;
        const bool act0 = (qw0 + 15 >= tb);     // strip has any unmasked key
        const bool act1 = (qw1 + 15 >= tb);
        if (!act1) return;                      // act0 implies act1's superset; both dead

        __builtin_amdgcn_s_setprio(1);

        // ---- K fragments (shared by both strips)
        bf16x8 kf[8];
        #pragma unroll
        for (int s = 0; s < 2; ++s)
            #pragma unroll
            for (int ni = 0; ni < 2; ++ni)
                #pragma unroll
                for (int dk = 0; dk < 2; ++dk)
                    kf[s * 4 + ni * 2 + dk] = *(const bf16x8*)(Kb
                        + (s * 32 + ni * 16 + c) * 128 + ((dk * 64 + g * 16) ^ swz));

        // ---- QK^T for both strips
        f32x4 s0A[2] = {}, s0B[2] = {}, s1A[2] = {}, s1B[2] = {};
        if (act0) {
            #pragma unroll
            for (int ni = 0; ni < 2; ++ni)
                #pragma unroll
                for (int dk = 0; dk < 2; ++dk) {
                    s0A[ni] = mfma16(kf[ni * 2 + dk],     qf0[dk], s0A[ni]);
                    s0B[ni] = mfma16(kf[4 + ni * 2 + dk], qf0[dk], s0B[ni]);
                }
        }
        #pragma unroll
        for (int ni = 0; ni < 2; ++ni)
            #pragma unroll
            for (int dk = 0; dk < 2; ++dk) {
                s1A[ni] = mfma16(kf[ni * 2 + dk],     qf1[dk], s1A[ni]);
                s1B[ni] = mfma16(kf[4 + ni * 2 + dk], qf1[dk], s1B[ni]);
            }

        // ---- softmax + ptrans per strip (mask only in diagonal zone)
        const bool dm0 = (tb + 63 > qw0);
        const bool dm1 = (tb + 63 > qw1);
        bf16x8 pf0A, pf0B, pf1A, pf1B;
        bool sk0 = true, sk1 = true;
        float al0 = 1.f, al1 = 1.f;
        if (act0) al0 = strip_sm(s0A, s0B, tb, qw0, dm0, m0, l0, pf0A, pf0B, sk0);
        al1 = strip_sm(s1A, s1B, tb, qw1, dm1, m1, l1, pf1A, pf1B, sk1);

        // ---- PV: V fragments shared by both strips
        #pragma unroll
        for (int dn = 0; dn < 4; ++dn) {
            const int row = dn * 16 + c;
            const bf16x8 vA = *(const bf16x8*)(Vb + row * 128 + ((g * 16)      ^ swz));
            const bf16x8 vB = *(const bf16x8*)(Vb + row * 128 + ((64 + g * 16) ^ swz));
            if (act0) {
                if (!sk0) {
                    #pragma unroll
                    for (int r = 0; r < 4; ++r)
                        oacc0[dn][r] *= al0;
                }
                oacc0[dn] = mfma16(vA, pf0A, oacc0[dn]);
                oacc0[dn] = mfma16(vB, pf0B, oacc0[dn]);
            }
            if (!sk1) {
                #pragma unroll
                for (int r = 0; r < 4; ++r)
                    oacc1[dn][r] *= al1;
            }
            oacc1[dn] = mfma16(vA, pf1A, oacc1[dn]);
            oacc1[dn] = mfma16(vB, pf1B, oacc1[dn]);
        }

        __builtin_amdgcn_s_setprio(0);
    };

    // 2x-unrolled double-buffer pipeline (nt is even)
    stage(0, 0);
    __syncthreads();
    for (int ti = 0; ti < nt; ti += 2) {
        stage(1, (ti + 1) << 6);
        compute(Ks[0], Vs[0], ti << 6);
        __syncthreads();
        if (ti + 2 < nt) stage(0, (ti + 2) << 6);
        compute(Ks[1], Vs[1], (ti + 1) << 6);
        __syncthreads();
    }

    // ---- epilogue: O[q][d = dn*16 + g*4 + r] for both strips
    const float li0 = 1.f / l0;
    const float li1 = 1.f / l1;
    const size_t ro0 = (size_t)(b * T_ + qw0 + c) * D_ + h * 64;
    const size_t ro1 = (size_t)(b * T_ + qw1 + c) * D_ + h * 64;
    #pragma unroll
    for (int dn = 0; dn < 4; ++dn) {
        uint2 st0, st1;
        st0.x = (unsigned int)f2bf(oacc0[dn][0] * li0)
              | ((unsigned int)f2bf(oacc0[dn][1] * li0) << 16);
        st0.y = (unsigned int)f2bf(oacc0[dn][2] * li0)
              | ((unsigned int)f2bf(oacc0[dn][3] * li0) << 16);
        st1.x = (unsigned int)f2bf(oacc1[dn][0] * li1)
              | ((unsigned int)f2bf(oacc1[dn][1] * li1) << 16);
        st1.y = (unsigned int)f2bf(oacc1[dn][2] * li1)
              | ((unsigned int)f2bf(oacc1[dn][3] * li1) << 16);
        *(uint2*)(Y + ro0 + dn * 16 + g * 4) = st0;
        *(uint2*)(Y + ro1 + dn * 16 + g * 4) = st1;
    }
}

// ---------------------------------------------------------------------------
// Output projection:  out = Y @ Wp^T + bp.  Y bf16[8192,1024]; out fp32.
// ---------------------------------------------------------------------------
__global__ __launch_bounds__(256, 2)
void proj_kernel(const unsigned short* __restrict__ Yin,
                 const unsigned short* __restrict__ Wp,
                 const float* __restrict__ bp,
                 float* __restrict__ Out)
{
    __shared__ unsigned short As[128 * 64];
    __shared__ unsigned short Bs[128 * 64];

    const int m0 = blockIdx.x * 128;
    const int n0 = blockIdx.y * 128;
    const int tid  = threadIdx.x;
    const int lane = tid & 63;
    const int wv   = tid >> 6;
    const int wr   = (wv >> 1) * 64;
    const int wc   = (wv & 1) * 64;
    const int g    = lane >> 4;
    const int c    = lane & 15;

    f32x4 acc[4][4] = {};

    for (int k0 = 0; k0 < D_; k0 += 64) {
        #pragma unroll
        for (int i = 0; i < 4; ++i) {
            const int flat = i * 2048 + tid * 8;
            const int row = flat >> 6, col = flat & 63;
            gl_lds16(Yin + (size_t)(m0 + row) * D_ + k0 + col, As + flat);
            gl_lds16(Wp  + (size_t)(n0 + row) * D_ + k0 + col, Bs + flat);
        }
        __syncthreads();
        #pragma unroll
        for (int kk = 0; kk < 64; kk += 32) {
            bf16x8 af[4], bg[4];
            #pragma unroll
            for (int mi = 0; mi < 4; ++mi)
                af[mi] = *(const bf16x8*)(As + (wr + mi * 16 + c) * 64 + kk + g * 8);
            #pragma unroll
            for (int ni = 0; ni < 4; ++ni)
                bg[ni] = *(const bf16x8*)(Bs + (wc + ni * 16 + c) * 64 + kk + g * 8);
            #pragma unroll
            for (int mi = 0; mi < 4; ++mi)
                #pragma unroll
                for (int ni = 0; ni < 4; ++ni)
                    acc[mi][ni] = mfma16(af[mi], bg[ni], acc[mi][ni]);
        }
        __syncthreads();
    }

    #pragma unroll
    for (int mi = 0; mi < 4; ++mi) {
        #pragma unroll
        for (int ni = 0; ni < 4; ++ni) {
            const int n = n0 + wc + ni * 16 + c;
            const float bb = bp[n];
            #pragma unroll
            for (int r = 0; r < 4; ++r) {
                const int m = m0 + wr + mi * 16 + g * 4 + r;
                Out[(size_t)m * D_ + n] = acc[mi][ni][r] + bb;
            }
        }
    }
}

// ---------------------------------------------------------------------------
extern "C" void kernel_launch(void* const* d_in, const int* in_sizes, int n_in,
                              void* d_out, int out_size, void* d_ws, size_t ws_size,
                              hipStream_t stream) {
    const float* x  = (const float*)d_in[0];
    const float* Wq = (const float*)d_in[1];
    const float* Wk = (const float*)d_in[2];
    const float* Wv = (const float*)d_in[3];
    const float* Wp = (const float*)d_in[4];
    const float* bp = (const float*)d_in[5];
    float* out = (float*)d_out;

    const size_t SZ  = (size_t)M_ * D_;      // 8388608
    const size_t WSZ = (size_t)D_ * D_;      // 1048576
    unsigned short* ws = (unsigned short*)d_ws;
    unsigned short* XB  = ws;                 // also Y after qkv
    unsigned short* WQB = XB  + SZ;
    unsigned short* WKB = WQB + WSZ;
    unsigned short* WVB = WKB + WSZ;
    unsigned short* WPB = WVB + WSZ;
    unsigned short* Qw  = WPB + WSZ;
    unsigned short* Kw  = Qw + SZ;
    unsigned short* Vw  = Kw + SZ;            // V^T [B,H,HD,T]
    unsigned short* Yw  = XB;                 // overlay: x_bf16 dead after qkv

    dim3 blk(256);
    cvt_kernel <<<dim3(SZ / 1024),     blk, 0, stream>>>(x, XB);
    cvtw_kernel<<<dim3(WSZ / 1024, 4), blk, 0, stream>>>(Wq, Wk, Wv, Wp, WQB, WKB, WVB, WPB);

    qkv_kernel <<<dim3(M_ / 128, 24), blk, 0, stream>>>(XB, WQB, WKB, WVB, Qw, Kw, Vw);
    attn_kernel<<<dim3(B_ * H_, 16), blk, 0, stream>>>(Qw, Kw, Vw, Yw);
    proj_kernel<<<dim3(M_ / 128, D_ / 128), blk, 0, stream>>>(Yw, WPB, bp, out);
}

// Round 14
// 207.427 us; speedup vs baseline: 1.0155x; 1.0155x over previous
//
#include <hip/hip_runtime.h>
#include <hip/hip_bf16.h>
#include <math.h>

// Problem: CausalSelfAttention  B=4 T=2048 D=1024 H=16 HD=64
// d_in: fp32 x[4,2048,1024], Wq,Wk,Wv,Wp[1024,1024], bp[1024]; d_out: fp32 y.
// Pipeline: cvt(fp32->bf16 into ws) -> qkv -> attn -> proj.
// V stored TRANSPOSED [B,H,HD,T]. attn v12 = round-12 per-wave body
// (verified: LDS dbuf, 3-bit XOR swizzle both-sides, swapped QK/PV, ptrans,
// defer-max, setprio) in an 8-wave/512-thread block: one 128-row q-tile per
// block, each wave owns 16 rows -> per-wave state unchanged (no spill), but
// each staged K/V tile feeds 2x the q-rows; 4 blocks/CU (100% occupancy).

#define B_  4
#define T_  2048
#define D_  1024
#define H_  16
#define HD_ 64
#define M_  (B_ * T_)   // 8192 rows

typedef short bf16x8 __attribute__((ext_vector_type(8)));
typedef float f32x4  __attribute__((ext_vector_type(4)));

__device__ __forceinline__ f32x4 mfma16(bf16x8 a, bf16x8 b, f32x4 c) {
    return __builtin_amdgcn_mfma_f32_16x16x32_bf16(a, b, c, 0, 0, 0);
}

__device__ __forceinline__ void gl_lds16(const unsigned short* g, unsigned short* l) {
    __builtin_amdgcn_global_load_lds(
        (const __attribute__((address_space(1))) void*)g,
        (__attribute__((address_space(3))) void*)l, 16, 0, 0);
}

__device__ __forceinline__ unsigned short f2bf(float f) {
    union { __hip_bfloat16 h; unsigned short u; } cv;
    cv.h = __float2bfloat16(f);
    return cv.u;
}
__device__ __forceinline__ float bf2f(unsigned short u) {
    return __uint_as_float(((unsigned)u) << 16);
}
__device__ __forceinline__ float exp2_fast(float x) {
    return __builtin_amdgcn_exp2f(x);   // v_exp_f32: 2^x
}

struct su4 { unsigned short x, y, z, w; };

// ---------------------------------------------------------------------------
// Single fp32->bf16 conversion kernel for x + all 4 weights.
// Destinations are contiguous in ws (XB | WQB | WKB | WVB | WPB) -> flat dst.
// ---------------------------------------------------------------------------
__global__ __launch_bounds__(256)
void cvt_all_kernel(const float* __restrict__ x,
                    const float* __restrict__ Wq, const float* __restrict__ Wk,
                    const float* __restrict__ Wv, const float* __restrict__ Wp,
                    unsigned short* __restrict__ dst) {
    const int i = blockIdx.x * 256 + threadIdx.x;   // float4 index, < 3145728
    const float* src;
    int j;
    if (i < 2097152) {                              // x: 8388608 elems / 4
        src = x; j = i;
    } else {
        const int k = i - 2097152;
        const int wsel = k >> 18;                   // 262144 float4 per weight
        j = k & 262143;
        src = (wsel == 0) ? Wq : (wsel == 1) ? Wk : (wsel == 2) ? Wv : Wp;
    }
    const float4 v = ((const float4*)src)[j];
    su4 o;
    o.x = f2bf(v.x); o.y = f2bf(v.y); o.z = f2bf(v.z); o.w = f2bf(v.w);
    ((su4*)dst)[i] = o;
}

// ---------------------------------------------------------------------------
// Fused QKV GEMM: C = X @ W^T.  Q,K scattered to [B,H,T,HD]; V to [B,H,HD,T]
// via operand-swapped MFMA (acc holds C^T for the V section).
// ---------------------------------------------------------------------------
__global__ __launch_bounds__(256, 2)
void qkv_kernel(const unsigned short* __restrict__ X,
                const unsigned short* __restrict__ Wq,
                const unsigned short* __restrict__ Wk,
                const unsigned short* __restrict__ Wv,
                unsigned short* __restrict__ Qo,
                unsigned short* __restrict__ Ko,
                unsigned short* __restrict__ Vo)
{
    __shared__ unsigned short As[128 * 64];
    __shared__ unsigned short Bs[128 * 64];

    const int m0 = blockIdx.x * 128;
    const int by = blockIdx.y;
    const unsigned short* W = (by < 8) ? Wq : (by < 16) ? Wk : Wv;
    unsigned short*       O = (by < 8) ? Qo : (by < 16) ? Ko : Vo;
    const int n0   = (by & 7) * 128;
    const bool vsec = (by >= 16);
    const int tid  = threadIdx.x;
    const int lane = tid & 63;
    const int wv   = tid >> 6;
    const int wr   = (wv >> 1) * 64;
    const int wc   = (wv & 1) * 64;
    const int g    = lane >> 4;
    const int c    = lane & 15;

    f32x4 acc[4][4] = {};

    for (int k0 = 0; k0 < D_; k0 += 64) {
        #pragma unroll
        for (int i = 0; i < 4; ++i) {
            const int flat = i * 2048 + tid * 8;
            const int row = flat >> 6, col = flat & 63;
            gl_lds16(X + (size_t)(m0 + row) * D_ + k0 + col, As + flat);
            gl_lds16(W + (size_t)(n0 + row) * D_ + k0 + col, Bs + flat);
        }
        __syncthreads();
        #pragma unroll
        for (int kk = 0; kk < 64; kk += 32) {
            bf16x8 af[4], bg[4];
            #pragma unroll
            for (int mi = 0; mi < 4; ++mi)
                af[mi] = *(const bf16x8*)(As + (wr + mi * 16 + c) * 64 + kk + g * 8);
            #pragma unroll
            for (int ni = 0; ni < 4; ++ni)
                bg[ni] = *(const bf16x8*)(Bs + (wc + ni * 16 + c) * 64 + kk + g * 8);
            if (!vsec) {
                #pragma unroll
                for (int mi = 0; mi < 4; ++mi)
                    #pragma unroll
                    for (int ni = 0; ni < 4; ++ni)
                        acc[mi][ni] = mfma16(af[mi], bg[ni], acc[mi][ni]);
            } else {
                #pragma unroll
                for (int mi = 0; mi < 4; ++mi)
                    #pragma unroll
                    for (int ni = 0; ni < 4; ++ni)
                        acc[mi][ni] = mfma16(bg[ni], af[mi], acc[mi][ni]);
            }
        }
        __syncthreads();
    }

    if (!vsec) {
        #pragma unroll
        for (int mi = 0; mi < 4; ++mi)
            #pragma unroll
            for (int ni = 0; ni < 4; ++ni)
                #pragma unroll
                for (int r = 0; r < 4; ++r) {
                    const int m = m0 + wr + mi * 16 + g * 4 + r;
                    const int n = n0 + wc + ni * 16 + c;
                    const int b = m >> 11, t = m & (T_ - 1);
                    const int h = n >> 6,  hd = n & 63;
                    O[((size_t)((b << 4) + h) * T_ + t) * HD_ + hd] = f2bf(acc[mi][ni][r]);
                }
    } else {
        #pragma unroll
        for (int mi = 0; mi < 4; ++mi)
            #pragma unroll
            for (int ni = 0; ni < 4; ++ni)
                #pragma unroll
                for (int r = 0; r < 4; ++r) {
                    const int n = n0 + wc + ni * 16 + g * 4 + r;
                    const int m = m0 + wr + mi * 16 + c;
                    const int b = m >> 11, t = m & (T_ - 1);
                    const int h = n >> 6,  hd = n & 63;
                    O[((size_t)((b << 4) + h) * HD_ + hd) * T_ + t] = f2bf(acc[mi][ni][r]);
                }
    }
}

// ---------------------------------------------------------------------------
// P-transpose helper (verified lane math).
// ---------------------------------------------------------------------------
__device__ __forceinline__ bf16x8 ptrans(const f32x4& p0, const f32x4& p1,
                                         int lane, int g, int c) {
    unsigned int P32[2][2];
    P32[0][0] = (unsigned int)f2bf(p0[0]) | ((unsigned int)f2bf(p0[1]) << 16);
    P32[0][1] = (unsigned int)f2bf(p0[2]) | ((unsigned int)f2bf(p0[3]) << 16);
    P32[1][0] = (unsigned int)f2bf(p1[0]) | ((unsigned int)f2bf(p1[1]) << 16);
    P32[1][1] = (unsigned int)f2bf(p1[2]) | ((unsigned int)f2bf(p1[3]) << 16);
    const int sl0 = c + ((lane & 16) << 1);
    const int sl1 = sl0 + 16;
    const int q00 = __shfl((int)P32[0][0], sl0), q10 = __shfl((int)P32[1][0], sl0);
    const int q01 = __shfl((int)P32[0][1], sl0), q11 = __shfl((int)P32[1][1], sl0);
    const int q02 = __shfl((int)P32[0][0], sl1), q12 = __shfl((int)P32[1][0], sl1);
    const int q03 = __shfl((int)P32[0][1], sl1), q13 = __shfl((int)P32[1][1], sl1);
    const bool nhi = (g & 2) != 0;
    union { unsigned int u[4]; bf16x8 v; } pf;
    pf.u[0] = nhi ? q10 : q00;
    pf.u[1] = nhi ? q11 : q01;
    pf.u[2] = nhi ? q12 : q02;
    pf.u[3] = nhi ? q13 : q03;
    return pf.v;
}

// ---------------------------------------------------------------------------
// Causal flash attention v12: 8 waves / 512 threads per block, one 128-row
// q-tile per block (wave w owns rows qt*128 + w*16 .. +15).  Round-12 per-
// wave body unchanged.  Double-buffered LDS staging shared by all 8 waves.
// LDS: 2 x (K[64][64] + V^T[64][64]) bf16 = 32KB -> 4 blocks/CU (100% occ).
// by->qt map {15..8,4..7,0..3} balances per-CU work under round-robin
// dispatch (each CU's 4 blocks sum to 30 q-tiles).
// ---------------------------------------------------------------------------
__global__ __launch_bounds__(512, 8)
void attn_kernel(const unsigned short* __restrict__ Q,
                 const unsigned short* __restrict__ K,
                 const unsigned short* __restrict__ VT,
                 unsigned short* __restrict__ Y)
{
    __shared__ unsigned short Ks[2][4096];   // K tiles, swizzled
    __shared__ unsigned short Vs[2][4096];   // V^T tiles, swizzled

    const int bh = blockIdx.x;          // fast axis -> XCD panel residency
    const int by = blockIdx.y;          // 0..15
    const int qt = (by < 8) ? (15 - by) : (by < 12) ? (by - 4) : (by - 12);
    const unsigned short* Qp  = Q  + (size_t)bh * T_ * HD_;
    const unsigned short* Kp  = K  + (size_t)bh * T_ * HD_;
    const unsigned short* VTp = VT + (size_t)bh * HD_ * T_;
    const int b = bh >> 4, h = bh & 15;

    const int tid  = threadIdx.x;
    const int lane = tid & 63;
    const int w    = tid >> 6;          // wave 0..7
    const int g    = lane >> 4;
    const int c    = lane & 15;
    const float SC = 0.18033688011112042f;   // (1/sqrt(64)) * log2(e)

    const int qw = qt * 128 + w * 16;   // this wave's q-row base
    const int nt = 2 * qt + 2;          // 64-key tiles (even)

    // Staging constants: 512 threads x one 16B segment per 8KB buffer
    const int L    = tid * 16;
    const int srow = L >> 7;                            // 0..63
    const int scol = (L & 127) ^ ((srow & 7) << 4);     // pre-swizzled src col (bytes)

    // Q as B-operand frags, pre-scaled (log2 domain)
    bf16x8 qf[2];
    #pragma unroll
    for (int dk = 0; dk < 2; ++dk) {
        bf16x8 t = *(const bf16x8*)(Qp + (size_t)(qw + c) * HD_ + dk * 32 + g * 8);
        #pragma unroll
        for (int j = 0; j < 8; ++j)
            t[j] = (short)f2bf(bf2f((unsigned short)t[j]) * SC);
        qf[dk] = t;
    }

    float m_l = -1e30f, l_l = 0.f;
    f32x4 oacc[4] = {};
    const int swz = (c & 7) << 4;       // per-lane read swizzle (bytes)

    // stage one 64-key tile into buffer `buf`
    auto stage = [&](int buf, int tb) {
        gl_lds16(Kp + (size_t)(tb + srow) * HD_ + (scol >> 1), &Ks[buf][L >> 1]);
        gl_lds16(VTp + (size_t)srow * T_ + tb + (scol >> 1),   &Vs[buf][L >> 1]);
    };

    // compute one 64-key tile from the given buffers (round-12 body)
    auto compute = [&](const unsigned short* Kbuf, const unsigned short* Vbuf, int tb) {
        if (tb > qw + 15) return;       // wave fully masked (last tile, low w)
        const char* Kb = (const char*)Kbuf;
        const char* Vb = (const char*)Vbuf;
        const bool dm = (tb + 63 > qw); // diagonal-zone masking needed

        __builtin_amdgcn_s_setprio(1);

        // ---- QK^T (swapped): sA (keys tb..tb+31), sB (tb+32..tb+63)
        f32x4 sA[2] = {}, sB[2] = {};
        #pragma unroll
        for (int ni = 0; ni < 2; ++ni)
            #pragma unroll
            for (int dk = 0; dk < 2; ++dk) {
                const int col = (dk * 64 + g * 16) ^ swz;
                const bf16x8 kA = *(const bf16x8*)(Kb + (ni * 16 + c) * 128 + col);
                const bf16x8 kB = *(const bf16x8*)(Kb + (32 + ni * 16 + c) * 128 + col);
                sA[ni] = mfma16(kA, qf[dk], sA[ni]);
                sB[ni] = mfma16(kB, qf[dk], sB[ni]);
            }

        // ---- mask (diagonal zone only)
        if (dm) {
            #pragma unroll
            for (int ni = 0; ni < 2; ++ni)
                #pragma unroll
                for (int r = 0; r < 4; ++r) {
                    const int kA = tb + ni * 16 + g * 4 + r;
                    sA[ni][r] = (kA      <= qw + c) ? sA[ni][r] : -1e30f;
                    sB[ni][r] = (kA + 32 <= qw + c) ? sB[ni][r] : -1e30f;
                }
        }

        // ---- online softmax (per-lane over 16 vals + 2 shuffles) + defer-max
        float pmax = sA[0][0];
        #pragma unroll
        for (int ni = 0; ni < 2; ++ni)
            #pragma unroll
            for (int r = 0; r < 4; ++r) {
                pmax = fmaxf(pmax, sA[ni][r]);
                pmax = fmaxf(pmax, sB[ni][r]);
            }
        pmax = fmaxf(pmax, __shfl_xor(pmax, 16));
        pmax = fmaxf(pmax, __shfl_xor(pmax, 32));

        const bool skip = __all(pmax - m_l <= 8.0f);
        float al = 1.f;
        if (!skip) {
            const float mn = fmaxf(m_l, pmax);
            al = exp2_fast(m_l - mn);
            m_l = mn;
        }

        float rs = 0.f;
        #pragma unroll
        for (int ni = 0; ni < 2; ++ni)
            #pragma unroll
            for (int r = 0; r < 4; ++r) {
                const float eA = exp2_fast(sA[ni][r] - m_l);
                const float eB = exp2_fast(sB[ni][r] - m_l);
                sA[ni][r] = eA; sB[ni][r] = eB;
                rs += eA + eB;
            }
        rs += __shfl_xor(rs, 16);
        rs += __shfl_xor(rs, 32);
        l_l = l_l * al + rs;

        // ---- P transpose to PV A-fragments
        const bf16x8 pfA = ptrans(sA[0], sA[1], lane, g, c);
        const bf16x8 pfB = ptrans(sB[0], sB[1], lane, g, c);

        // ---- rescale (skipped when deferred) + PV (swapped)
        #pragma unroll
        for (int dn = 0; dn < 4; ++dn) {
            const int row = dn * 16 + c;
            const bf16x8 vA = *(const bf16x8*)(Vb + row * 128 + ((g * 16)      ^ swz));
            const bf16x8 vB = *(const bf16x8*)(Vb + row * 128 + ((64 + g * 16) ^ swz));
            if (!skip) {
                #pragma unroll
                for (int r = 0; r < 4; ++r)
                    oacc[dn][r] *= al;
            }
            oacc[dn] = mfma16(vA, pfA, oacc[dn]);
            oacc[dn] = mfma16(vB, pfB, oacc[dn]);
        }

        __builtin_amdgcn_s_setprio(0);
    };

    // 2x-unrolled double-buffer pipeline (nt is even)
    stage(0, 0);
    __syncthreads();
    for (int ti = 0; ti < nt; ti += 2) {
        stage(1, (ti + 1) << 6);
        compute(Ks[0], Vs[0], ti << 6);
        __syncthreads();
        if (ti + 2 < nt) stage(0, (ti + 2) << 6);
        compute(Ks[1], Vs[1], (ti + 1) << 6);
        __syncthreads();
    }

    // ---- epilogue: O[q = qw+c][d = dn*16 + g*4 + r]
    const float li = 1.f / l_l;
    const size_t rowoff = (size_t)(b * T_ + qw + c) * D_ + h * 64;
    #pragma unroll
    for (int dn = 0; dn < 4; ++dn) {
        const unsigned int u0 = (unsigned int)f2bf(oacc[dn][0] * li)
                              | ((unsigned int)f2bf(oacc[dn][1] * li) << 16);
        const unsigned int u1 = (unsigned int)f2bf(oacc[dn][2] * li)
                              | ((unsigned int)f2bf(oacc[dn][3] * li) << 16);
        uint2 st; st.x = u0; st.y = u1;
        *(uint2*)(Y + rowoff + dn * 16 + g * 4) = st;
    }
}

// ---------------------------------------------------------------------------
// Output projection:  out = Y @ Wp^T + bp.  Y bf16[8192,1024]; out fp32.
// ---------------------------------------------------------------------------
__global__ __launch_bounds__(256, 2)
void proj_kernel(const unsigned short* __restrict__ Yin,
                 const unsigned short* __restrict__ Wp,
                 const float* __restrict__ bp,
                 float* __restrict__ Out)
{
    __shared__ unsigned short As[128 * 64];
    __shared__ unsigned short Bs[128 * 64];

    const int m0 = blockIdx.x * 128;
    const int n0 = blockIdx.y * 128;
    const int tid  = threadIdx.x;
    const int lane = tid & 63;
    const int wv   = tid >> 6;
    const int wr   = (wv >> 1) * 64;
    const int wc   = (wv & 1) * 64;
    const int g    = lane >> 4;
    const int c    = lane & 15;

    f32x4 acc[4][4] = {};

    for (int k0 = 0; k0 < D_; k0 += 64) {
        #pragma unroll
        for (int i = 0; i < 4; ++i) {
            const int flat = i * 2048 + tid * 8;
            const int row = flat >> 6, col = flat & 63;
            gl_lds16(Yin + (size_t)(m0 + row) * D_ + k0 + col, As + flat);
            gl_lds16(Wp  + (size_t)(n0 + row) * D_ + k0 + col, Bs + flat);
        }
        __syncthreads();
        #pragma unroll
        for (int kk = 0; kk < 64; kk += 32) {
            bf16x8 af[4], bg[4];
            #pragma unroll
            for (int mi = 0; mi < 4; ++mi)
                af[mi] = *(const bf16x8*)(As + (wr + mi * 16 + c) * 64 + kk + g * 8);
            #pragma unroll
            for (int ni = 0; ni < 4; ++ni)
                bg[ni] = *(const bf16x8*)(Bs + (wc + ni * 16 + c) * 64 + kk + g * 8);
            #pragma unroll
            for (int mi = 0; mi < 4; ++mi)
                #pragma unroll
                for (int ni = 0; ni < 4; ++ni)
                    acc[mi][ni] = mfma16(af[mi], bg[ni], acc[mi][ni]);
        }
        __syncthreads();
    }

    #pragma unroll
    for (int mi = 0; mi < 4; ++mi) {
        #pragma unroll
        for (int ni = 0; ni < 4; ++ni) {
            const int n = n0 + wc + ni * 16 + c;
            const float bb = bp[n];
            #pragma unroll
            for (int r = 0; r < 4; ++r) {
                const int m = m0 + wr + mi * 16 + g * 4 + r;
                Out[(size_t)m * D_ + n] = acc[mi][ni][r] + bb;
            }
        }
    }
}

// ---------------------------------------------------------------------------
extern "C" void kernel_launch(void* const* d_in, const int* in_sizes, int n_in,
                              void* d_out, int out_size, void* d_ws, size_t ws_size,
                              hipStream_t stream) {
    const float* x  = (const float*)d_in[0];
    const float* Wq = (const float*)d_in[1];
    const float* Wk = (const float*)d_in[2];
    const float* Wv = (const float*)d_in[3];
    const float* Wp = (const float*)d_in[4];
    const float* bp = (const float*)d_in[5];
    float* out = (float*)d_out;

    const size_t SZ  = (size_t)M_ * D_;      // 8388608
    const size_t WSZ = (size_t)D_ * D_;      // 1048576
    unsigned short* ws = (unsigned short*)d_ws;
    unsigned short* XB  = ws;                 // also Y after qkv
    unsigned short* WQB = XB  + SZ;
    unsigned short* WKB = WQB + WSZ;
    unsigned short* WVB = WKB + WSZ;
    unsigned short* WPB = WVB + WSZ;
    unsigned short* Qw  = WPB + WSZ;
    unsigned short* Kw  = Qw + SZ;
    unsigned short* Vw  = Kw + SZ;            // V^T [B,H,HD,T]
    unsigned short* Yw  = XB;                 // overlay: x_bf16 dead after qkv

    dim3 blk(256);
    // one conversion launch: (SZ + 4*WSZ)/4 float4s / 256 threads = 12288 blocks
    cvt_all_kernel<<<dim3(12288), blk, 0, stream>>>(x, Wq, Wk, Wv, Wp, ws);

    qkv_kernel <<<dim3(M_ / 128, 24), blk, 0, stream>>>(XB, WQB, WKB, WVB, Qw, Kw, Vw);
    attn_kernel<<<dim3(B_ * H_, 16), dim3(512), 0, stream>>>(Qw, Kw, Vw, Yw);
    proj_kernel<<<dim3(M_ / 128, D_ / 128), blk, 0, stream>>>(Yw, WPB, bp, out);
}

// Round 15
// 194.528 us; speedup vs baseline: 1.0828x; 1.0663x over previous
//
#include <hip/hip_runtime.h>
#include <hip/hip_bf16.h>
#include <math.h>

// Problem: CausalSelfAttention  B=4 T=2048 D=1024 H=16 HD=64
// d_in: fp32 x[4,2048,1024], Wq,Wk,Wv,Wp[1024,1024], bp[1024]; d_out: fp32 y.
// Pipeline: cvt_all(fp32->bf16) -> qkv -> attn -> proj.
// V stored TRANSPOSED [B,H,HD,T]. attn = round-12 verified body (best: 92.5us):
// 4 waves, 16 q-rows/wave, KVBLK=64, LDS dbuf, 3-bit XOR swizzle both-sides,
// swapped QK/PV, ptrans, defer-max, setprio, LPT grid (64 x 32).

#define B_  4
#define T_  2048
#define D_  1024
#define H_  16
#define HD_ 64
#define M_  (B_ * T_)   // 8192 rows

typedef short bf16x8 __attribute__((ext_vector_type(8)));
typedef float f32x4  __attribute__((ext_vector_type(4)));

__device__ __forceinline__ f32x4 mfma16(bf16x8 a, bf16x8 b, f32x4 c) {
    return __builtin_amdgcn_mfma_f32_16x16x32_bf16(a, b, c, 0, 0, 0);
}

__device__ __forceinline__ void gl_lds16(const unsigned short* g, unsigned short* l) {
    __builtin_amdgcn_global_load_lds(
        (const __attribute__((address_space(1))) void*)g,
        (__attribute__((address_space(3))) void*)l, 16, 0, 0);
}

__device__ __forceinline__ unsigned short f2bf(float f) {
    union { __hip_bfloat16 h; unsigned short u; } cv;
    cv.h = __float2bfloat16(f);
    return cv.u;
}
__device__ __forceinline__ float bf2f(unsigned short u) {
    return __uint_as_float(((unsigned)u) << 16);
}
__device__ __forceinline__ float exp2_fast(float x) {
    return __builtin_amdgcn_exp2f(x);   // v_exp_f32: 2^x
}

struct su4 { unsigned short x, y, z, w; };

// ---------------------------------------------------------------------------
// Single fp32->bf16 conversion kernel for x + all 4 weights.
// Destinations are contiguous in ws (XB | WQB | WKB | WVB | WPB) -> flat dst.
// ---------------------------------------------------------------------------
__global__ __launch_bounds__(256)
void cvt_all_kernel(const float* __restrict__ x,
                    const float* __restrict__ Wq, const float* __restrict__ Wk,
                    const float* __restrict__ Wv, const float* __restrict__ Wp,
                    unsigned short* __restrict__ dst) {
    const int i = blockIdx.x * 256 + threadIdx.x;   // float4 index, < 3145728
    const float* src;
    int j;
    if (i < 2097152) {                              // x: 8388608 elems / 4
        src = x; j = i;
    } else {
        const int k = i - 2097152;
        const int wsel = k >> 18;                   // 262144 float4 per weight
        j = k & 262143;
        src = (wsel == 0) ? Wq : (wsel == 1) ? Wk : (wsel == 2) ? Wv : Wp;
    }
    const float4 v = ((const float4*)src)[j];
    su4 o;
    o.x = f2bf(v.x); o.y = f2bf(v.y); o.z = f2bf(v.z); o.w = f2bf(v.w);
    ((su4*)dst)[i] = o;
}

// ---------------------------------------------------------------------------
// Fused QKV GEMM: C = X @ W^T.  Q,K scattered to [B,H,T,HD]; V to [B,H,HD,T]
// via operand-swapped MFMA (acc holds C^T for the V section).
// ---------------------------------------------------------------------------
__global__ __launch_bounds__(256, 2)
void qkv_kernel(const unsigned short* __restrict__ X,
                const unsigned short* __restrict__ Wq,
                const unsigned short* __restrict__ Wk,
                const unsigned short* __restrict__ Wv,
                unsigned short* __restrict__ Qo,
                unsigned short* __restrict__ Ko,
                unsigned short* __restrict__ Vo)
{
    __shared__ unsigned short As[128 * 64];
    __shared__ unsigned short Bs[128 * 64];

    const int m0 = blockIdx.x * 128;
    const int by = blockIdx.y;
    const unsigned short* W = (by < 8) ? Wq : (by < 16) ? Wk : Wv;
    unsigned short*       O = (by < 8) ? Qo : (by < 16) ? Ko : Vo;
    const int n0   = (by & 7) * 128;
    const bool vsec = (by >= 16);
    const int tid  = threadIdx.x;
    const int lane = tid & 63;
    const int wv   = tid >> 6;
    const int wr   = (wv >> 1) * 64;
    const int wc   = (wv & 1) * 64;
    const int g    = lane >> 4;
    const int c    = lane & 15;

    f32x4 acc[4][4] = {};

    for (int k0 = 0; k0 < D_; k0 += 64) {
        #pragma unroll
        for (int i = 0; i < 4; ++i) {
            const int flat = i * 2048 + tid * 8;
            const int row = flat >> 6, col = flat & 63;
            gl_lds16(X + (size_t)(m0 + row) * D_ + k0 + col, As + flat);
            gl_lds16(W + (size_t)(n0 + row) * D_ + k0 + col, Bs + flat);
        }
        __syncthreads();
        #pragma unroll
        for (int kk = 0; kk < 64; kk += 32) {
            bf16x8 af[4], bg[4];
            #pragma unroll
            for (int mi = 0; mi < 4; ++mi)
                af[mi] = *(const bf16x8*)(As + (wr + mi * 16 + c) * 64 + kk + g * 8);
            #pragma unroll
            for (int ni = 0; ni < 4; ++ni)
                bg[ni] = *(const bf16x8*)(Bs + (wc + ni * 16 + c) * 64 + kk + g * 8);
            if (!vsec) {
                #pragma unroll
                for (int mi = 0; mi < 4; ++mi)
                    #pragma unroll
                    for (int ni = 0; ni < 4; ++ni)
                        acc[mi][ni] = mfma16(af[mi], bg[ni], acc[mi][ni]);
            } else {
                #pragma unroll
                for (int mi = 0; mi < 4; ++mi)
                    #pragma unroll
                    for (int ni = 0; ni < 4; ++ni)
                        acc[mi][ni] = mfma16(bg[ni], af[mi], acc[mi][ni]);
            }
        }
        __syncthreads();
    }

    if (!vsec) {
        #pragma unroll
        for (int mi = 0; mi < 4; ++mi)
            #pragma unroll
            for (int ni = 0; ni < 4; ++ni)
                #pragma unroll
                for (int r = 0; r < 4; ++r) {
                    const int m = m0 + wr + mi * 16 + g * 4 + r;
                    const int n = n0 + wc + ni * 16 + c;
                    const int b = m >> 11, t = m & (T_ - 1);
                    const int h = n >> 6,  hd = n & 63;
                    O[((size_t)((b << 4) + h) * T_ + t) * HD_ + hd] = f2bf(acc[mi][ni][r]);
                }
    } else {
        #pragma unroll
        for (int mi = 0; mi < 4; ++mi)
            #pragma unroll
            for (int ni = 0; ni < 4; ++ni)
                #pragma unroll
                for (int r = 0; r < 4; ++r) {
                    const int n = n0 + wc + ni * 16 + g * 4 + r;
                    const int m = m0 + wr + mi * 16 + c;
                    const int b = m >> 11, t = m & (T_ - 1);
                    const int h = n >> 6,  hd = n & 63;
                    O[((size_t)((b << 4) + h) * HD_ + hd) * T_ + t] = f2bf(acc[mi][ni][r]);
                }
    }
}

// ---------------------------------------------------------------------------
// P-transpose helper (verified lane math).
// ---------------------------------------------------------------------------
__device__ __forceinline__ bf16x8 ptrans(const f32x4& p0, const f32x4& p1,
                                         int lane, int g, int c) {
    unsigned int P32[2][2];
    P32[0][0] = (unsigned int)f2bf(p0[0]) | ((unsigned int)f2bf(p0[1]) << 16);
    P32[0][1] = (unsigned int)f2bf(p0[2]) | ((unsigned int)f2bf(p0[3]) << 16);
    P32[1][0] = (unsigned int)f2bf(p1[0]) | ((unsigned int)f2bf(p1[1]) << 16);
    P32[1][1] = (unsigned int)f2bf(p1[2]) | ((unsigned int)f2bf(p1[3]) << 16);
    const int sl0 = c + ((lane & 16) << 1);
    const int sl1 = sl0 + 16;
    const int q00 = __shfl((int)P32[0][0], sl0), q10 = __shfl((int)P32[1][0], sl0);
    const int q01 = __shfl((int)P32[0][1], sl0), q11 = __shfl((int)P32[1][1], sl0);
    const int q02 = __shfl((int)P32[0][0], sl1), q12 = __shfl((int)P32[1][0], sl1);
    const int q03 = __shfl((int)P32[0][1], sl1), q13 = __shfl((int)P32[1][1], sl1);
    const bool nhi = (g & 2) != 0;
    union { unsigned int u[4]; bf16x8 v; } pf;
    pf.u[0] = nhi ? q10 : q00;
    pf.u[1] = nhi ? q11 : q01;
    pf.u[2] = nhi ? q12 : q02;
    pf.u[3] = nhi ? q13 : q03;
    return pf.v;
}

// ---------------------------------------------------------------------------
// Causal flash attention (round-12 verified): double-buffered LDS staging,
// 2x-unrolled loop (compile-time buffer selection), 3-bit XOR swizzle,
// setprio, defer-max, LPT grid (64 x 32), 4 waves, 16 q-rows/wave.
// LDS: 2 x (K[64][64] + V^T[64][64]) bf16 = 32KB.
// Swizzle: phys_byte = row*128 + (log_byte ^ ((row&7)<<4)); staged via
// linear gl_lds dest + pre-swizzled global source (involution).
// ---------------------------------------------------------------------------
__global__ __launch_bounds__(256, 4)
void attn_kernel(const unsigned short* __restrict__ Q,
                 const unsigned short* __restrict__ K,
                 const unsigned short* __restrict__ VT,
                 unsigned short* __restrict__ Y)
{
    __shared__ unsigned short Ks[2][4096];   // K tiles, swizzled
    __shared__ unsigned short Vs[2][4096];   // V^T tiles, swizzled

    const int bh = blockIdx.x;          // fast axis -> XCD panel residency
    const int qt = 31 - blockIdx.y;     // LPT: heaviest q-tiles first
    const unsigned short* Qp  = Q  + (size_t)bh * T_ * HD_;
    const unsigned short* Kp  = K  + (size_t)bh * T_ * HD_;
    const unsigned short* VTp = VT + (size_t)bh * HD_ * T_;
    const int b = bh >> 4, h = bh & 15;

    const int tid  = threadIdx.x;
    const int lane = tid & 63;
    const int w    = tid >> 6;
    const int g    = lane >> 4;
    const int c    = lane & 15;
    const float SC = 0.18033688011112042f;   // (1/sqrt(64)) * log2(e)

    const int qw = qt * 64 + w * 16;
    const int nt = qt + 1;              // 64-key tiles; last is diagonal

    // Staging constants (two 16B segments per 8KB half-tile); 3-bit swizzle
    int srow[2], scol[2];
    #pragma unroll
    for (int i = 0; i < 2; ++i) {
        const int L = (i * 256 + tid) * 16;
        srow[i] = L >> 7;                                   // 0..63
        scol[i] = (L & 127) ^ ((srow[i] & 7) << 4);         // pre-swizzled src col (bytes)
    }

    // Q as B-operand frags, pre-scaled (log2 domain)
    bf16x8 qf[2];
    #pragma unroll
    for (int dk = 0; dk < 2; ++dk) {
        bf16x8 t = *(const bf16x8*)(Qp + (size_t)(qw + c) * HD_ + dk * 32 + g * 8);
        #pragma unroll
        for (int j = 0; j < 8; ++j)
            t[j] = (short)f2bf(bf2f((unsigned short)t[j]) * SC);
        qf[dk] = t;
    }

    float m_l = -1e30f, l_l = 0.f;
    f32x4 oacc[4] = {};
    const int swz = (c & 7) << 4;       // per-lane read swizzle (bytes)

    // stage one 64-key tile into buffer `buf`
    auto stage = [&](int buf, int tb) {
        #pragma unroll
        for (int i = 0; i < 2; ++i) {
            const int L = (i * 256 + tid) * 16;
            gl_lds16(Kp + (size_t)(tb + srow[i]) * HD_ + (scol[i] >> 1),
                     &Ks[buf][L >> 1]);
            gl_lds16(VTp + (size_t)srow[i] * T_ + tb + (scol[i] >> 1),
                     &Vs[buf][L >> 1]);
        }
    };

    // compute one 64-key tile from the given buffers
    auto compute = [&](const unsigned short* Kbuf, const unsigned short* Vbuf,
                       int tb, bool last) {
        const char* Kb = (const char*)Kbuf;
        const char* Vb = (const char*)Vbuf;

        __builtin_amdgcn_s_setprio(1);

        // ---- QK^T (swapped): sA (keys tb..tb+31), sB (tb+32..tb+63)
        f32x4 sA[2] = {}, sB[2] = {};
        #pragma unroll
        for (int ni = 0; ni < 2; ++ni)
            #pragma unroll
            for (int dk = 0; dk < 2; ++dk) {
                const int col = (dk * 64 + g * 16) ^ swz;
                const bf16x8 kA = *(const bf16x8*)(Kb + (ni * 16 + c) * 128 + col);
                const bf16x8 kB = *(const bf16x8*)(Kb + (32 + ni * 16 + c) * 128 + col);
                sA[ni] = mfma16(kA, qf[dk], sA[ni]);
                sB[ni] = mfma16(kB, qf[dk], sB[ni]);
            }

        // ---- mask (diagonal tile only)
        if (last) {
            #pragma unroll
            for (int ni = 0; ni < 2; ++ni)
                #pragma unroll
                for (int r = 0; r < 4; ++r) {
                    const int kA = tb + ni * 16 + g * 4 + r;
                    sA[ni][r] = (kA      <= qw + c) ? sA[ni][r] : -1e30f;
                    sB[ni][r] = (kA + 32 <= qw + c) ? sB[ni][r] : -1e30f;
                }
        }

        // ---- online softmax (per-lane over 16 vals + 2 shuffles) + defer-max
        float pmax = sA[0][0];
        #pragma unroll
        for (int ni = 0; ni < 2; ++ni)
            #pragma unroll
            for (int r = 0; r < 4; ++r) {
                pmax = fmaxf(pmax, sA[ni][r]);
                pmax = fmaxf(pmax, sB[ni][r]);
            }
        pmax = fmaxf(pmax, __shfl_xor(pmax, 16));
        pmax = fmaxf(pmax, __shfl_xor(pmax, 32));

        const bool skip = __all(pmax - m_l <= 8.0f);
        float al = 1.f;
        if (!skip) {
            const float mn = fmaxf(m_l, pmax);
            al = exp2_fast(m_l - mn);
            m_l = mn;
        }

        float rs = 0.f;
        #pragma unroll
        for (int ni = 0; ni < 2; ++ni)
            #pragma unroll
            for (int r = 0; r < 4; ++r) {
                const float eA = exp2_fast(sA[ni][r] - m_l);
                const float eB = exp2_fast(sB[ni][r] - m_l);
                sA[ni][r] = eA; sB[ni][r] = eB;
                rs += eA + eB;
            }
        rs += __shfl_xor(rs, 16);
        rs += __shfl_xor(rs, 32);
        l_l = l_l * al + rs;

        // ---- P transpose to PV A-fragments
        const bf16x8 pfA = ptrans(sA[0], sA[1], lane, g, c);
        const bf16x8 pfB = ptrans(sB[0], sB[1], lane, g, c);

        // ---- rescale (skipped when deferred) + PV (swapped)
        #pragma unroll
        for (int dn = 0; dn < 4; ++dn) {
            const int row = dn * 16 + c;
            const bf16x8 vA = *(const bf16x8*)(Vb + row * 128 + ((g * 16)      ^ swz));
            const bf16x8 vB = *(const bf16x8*)(Vb + row * 128 + ((64 + g * 16) ^ swz));
            if (!skip) {
                #pragma unroll
                for (int r = 0; r < 4; ++r)
                    oacc[dn][r] *= al;
            }
            oacc[dn] = mfma16(vA, pfA, oacc[dn]);
            oacc[dn] = mfma16(vB, pfB, oacc[dn]);
        }

        __builtin_amdgcn_s_setprio(0);
    };

    // 2x-unrolled double-buffer pipeline (compile-time buffer indices)
    stage(0, 0);
    __syncthreads();
    int ti = 0;
    for (;;) {
        if (ti + 1 < nt) stage(1, (ti + 1) << 6);
        compute(Ks[0], Vs[0], ti << 6, ti == nt - 1);
        __syncthreads();
        if (++ti >= nt) break;

        if (ti + 1 < nt) stage(0, (ti + 1) << 6);
        compute(Ks[1], Vs[1], ti << 6, ti == nt - 1);
        __syncthreads();
        if (++ti >= nt) break;
    }

    // ---- epilogue: O[q = qw+c][d = dn*16 + g*4 + r]
    const float li = 1.f / l_l;
    const size_t rowoff = (size_t)(b * T_ + qw + c) * D_ + h * 64;
    #pragma unroll
    for (int dn = 0; dn < 4; ++dn) {
        const unsigned int u0 = (unsigned int)f2bf(oacc[dn][0] * li)
                              | ((unsigned int)f2bf(oacc[dn][1] * li) << 16);
        const unsigned int u1 = (unsigned int)f2bf(oacc[dn][2] * li)
                              | ((unsigned int)f2bf(oacc[dn][3] * li) << 16);
        uint2 st; st.x = u0; st.y = u1;
        *(uint2*)(Y + rowoff + dn * 16 + g * 4) = st;
    }
}

// ---------------------------------------------------------------------------
// Output projection:  out = Y @ Wp^T + bp.  Y bf16[8192,1024]; out fp32.
// ---------------------------------------------------------------------------
__global__ __launch_bounds__(256, 2)
void proj_kernel(const unsigned short* __restrict__ Yin,
                 const unsigned short* __restrict__ Wp,
                 const float* __restrict__ bp,
                 float* __restrict__ Out)
{
    __shared__ unsigned short As[128 * 64];
    __shared__ unsigned short Bs[128 * 64];

    const int m0 = blockIdx.x * 128;
    const int n0 = blockIdx.y * 128;
    const int tid  = threadIdx.x;
    const int lane = tid & 63;
    const int wv   = tid >> 6;
    const int wr   = (wv >> 1) * 64;
    const int wc   = (wv & 1) * 64;
    const int g    = lane >> 4;
    const int c    = lane & 15;

    f32x4 acc[4][4] = {};

    for (int k0 = 0; k0 < D_; k0 += 64) {
        #pragma unroll
        for (int i = 0; i < 4; ++i) {
            const int flat = i * 2048 + tid * 8;
            const int row = flat >> 6, col = flat & 63;
            gl_lds16(Yin + (size_t)(m0 + row) * D_ + k0 + col, As + flat);
            gl_lds16(Wp  + (size_t)(n0 + row) * D_ + k0 + col, Bs + flat);
        }
        __syncthreads();
        #pragma unroll
        for (int kk = 0; kk < 64; kk += 32) {
            bf16x8 af[4], bg[4];
            #pragma unroll
            for (int mi = 0; mi < 4; ++mi)
                af[mi] = *(const bf16x8*)(As + (wr + mi * 16 + c) * 64 + kk + g * 8);
            #pragma unroll
            for (int ni = 0; ni < 4; ++ni)
                bg[ni] = *(const bf16x8*)(Bs + (wc + ni * 16 + c) * 64 + kk + g * 8);
            #pragma unroll
            for (int mi = 0; mi < 4; ++mi)
                #pragma unroll
                for (int ni = 0; ni < 4; ++ni)
                    acc[mi][ni] = mfma16(af[mi], bg[ni], acc[mi][ni]);
        }
        __syncthreads();
    }

    #pragma unroll
    for (int mi = 0; mi < 4; ++mi) {
        #pragma unroll
        for (int ni = 0; ni < 4; ++ni) {
            const int n = n0 + wc + ni * 16 + c;
            const float bb = bp[n];
            #pragma unroll
            for (int r = 0; r < 4; ++r) {
                const int m = m0 + wr + mi * 16 + g * 4 + r;
                Out[(size_t)m * D_ + n] = acc[mi][ni][r] + bb;
            }
        }
    }
}

// ---------------------------------------------------------------------------
extern "C" void kernel_launch(void* const* d_in, const int* in_sizes, int n_in,
                              void* d_out, int out_size, void* d_ws, size_t ws_size,
                              hipStream_t stream) {
    const float* x  = (const float*)d_in[0];
    const float* Wq = (const float*)d_in[1];
    const float* Wk = (const float*)d_in[2];
    const float* Wv = (const float*)d_in[3];
    const float* Wp = (const float*)d_in[4];
    const float* bp = (const float*)d_in[5];
    float* out = (float*)d_out;

    const size_t SZ  = (size_t)M_ * D_;      // 8388608
    const size_t WSZ = (size_t)D_ * D_;      // 1048576
    unsigned short* ws = (unsigned short*)d_ws;
    unsigned short* XB  = ws;                 // also Y after qkv
    unsigned short* WQB = XB  + SZ;
    unsigned short* WKB = WQB + WSZ;
    unsigned short* WVB = WKB + WSZ;
    unsigned short* WPB = WVB + WSZ;
    unsigned short* Qw  = WPB + WSZ;
    unsigned short* Kw  = Qw + SZ;
    unsigned short* Vw  = Kw + SZ;            // V^T [B,H,HD,T]
    unsigned short* Yw  = XB;                 // overlay: x_bf16 dead after qkv

    dim3 blk(256);
    // one conversion launch: (SZ + 4*WSZ)/4 float4s / 256 threads = 12288 blocks
    cvt_all_kernel<<<dim3(12288), blk, 0, stream>>>(x, Wq, Wk, Wv, Wp, ws);

    qkv_kernel <<<dim3(M_ / 128, 24), blk, 0, stream>>>(XB, WQB, WKB, WVB, Qw, Kw, Vw);
    attn_kernel<<<dim3(B_ * H_, T_ / 64), blk, 0, stream>>>(Qw, Kw, Vw, Yw);
    proj_kernel<<<dim3(M_ / 128, D_ / 128), blk, 0, stream>>>(Yw, WPB, bp, out);
}

// Round 16
// 180.463 us; speedup vs baseline: 1.1672x; 1.0779x over previous
//
#include <hip/hip_runtime.h>
#include <hip/hip_bf16.h>
#include <math.h>

// Problem: CausalSelfAttention  B=4 T=2048 D=1024 H=16 HD=64
// d_in: fp32 x[4,2048,1024], Wq,Wk,Wv,Wp[1024,1024], bp[1024]; d_out: fp32 y.
// Pipeline: cvt_all(fp32->bf16) -> qkv -> attn -> proj.
// V stored TRANSPOSED [B,H,HD,T]. attn v13: 32x32 MFMA shape — wave owns
// 32 q-rows; per 64-key tile: 8 mfma32 QK + 8 mfma32 PV on 16 LDS b128
// reads -> LDS reads / shuffles / softmax bookkeeping per q-row halved vs
// the 16x16 r12 body. Same verified staging/swizzle/dbuf/defer-max.
// 32x32 C layout (HW-verified m74/m101): col=lane&31, row=(reg&3)+8*(reg>>2)
// +4*(lane>>5). A/B frags: row|col=lane&31, k=(lane>>5)*8+j.

#define B_  4
#define T_  2048
#define D_  1024
#define H_  16
#define HD_ 64
#define M_  (B_ * T_)   // 8192 rows

typedef short bf16x8 __attribute__((ext_vector_type(8)));
typedef float f32x4  __attribute__((ext_vector_type(4)));
typedef float f32x16 __attribute__((ext_vector_type(16)));

__device__ __forceinline__ f32x4 mfma16(bf16x8 a, bf16x8 b, f32x4 c) {
    return __builtin_amdgcn_mfma_f32_16x16x32_bf16(a, b, c, 0, 0, 0);
}
__device__ __forceinline__ f32x16 mfma32(bf16x8 a, bf16x8 b, f32x16 c) {
    return __builtin_amdgcn_mfma_f32_32x32x16_bf16(a, b, c, 0, 0, 0);
}

__device__ __forceinline__ void gl_lds16(const unsigned short* g, unsigned short* l) {
    __builtin_amdgcn_global_load_lds(
        (const __attribute__((address_space(1))) void*)g,
        (__attribute__((address_space(3))) void*)l, 16, 0, 0);
}

__device__ __forceinline__ unsigned short f2bf(float f) {
    union { __hip_bfloat16 h; unsigned short u; } cv;
    cv.h = __float2bfloat16(f);
    return cv.u;
}
__device__ __forceinline__ float bf2f(unsigned short u) {
    return __uint_as_float(((unsigned)u) << 16);
}
__device__ __forceinline__ float exp2_fast(float x) {
    return __builtin_amdgcn_exp2f(x);   // v_exp_f32: 2^x
}

struct su4 { unsigned short x, y, z, w; };

// ---------------------------------------------------------------------------
// Single fp32->bf16 conversion kernel for x + all 4 weights.
// ---------------------------------------------------------------------------
__global__ __launch_bounds__(256)
void cvt_all_kernel(const float* __restrict__ x,
                    const float* __restrict__ Wq, const float* __restrict__ Wk,
                    const float* __restrict__ Wv, const float* __restrict__ Wp,
                    unsigned short* __restrict__ dst) {
    const int i = blockIdx.x * 256 + threadIdx.x;   // float4 index, < 3145728
    const float* src;
    int j;
    if (i < 2097152) {                              // x: 8388608 elems / 4
        src = x; j = i;
    } else {
        const int k = i - 2097152;
        const int wsel = k >> 18;                   // 262144 float4 per weight
        j = k & 262143;
        src = (wsel == 0) ? Wq : (wsel == 1) ? Wk : (wsel == 2) ? Wv : Wp;
    }
    const float4 v = ((const float4*)src)[j];
    su4 o;
    o.x = f2bf(v.x); o.y = f2bf(v.y); o.z = f2bf(v.z); o.w = f2bf(v.w);
    ((su4*)dst)[i] = o;
}

// ---------------------------------------------------------------------------
// Fused QKV GEMM: C = X @ W^T.  Q,K scattered to [B,H,T,HD]; V to [B,H,HD,T]
// via operand-swapped MFMA (acc holds C^T for the V section).
// ---------------------------------------------------------------------------
__global__ __launch_bounds__(256, 2)
void qkv_kernel(const unsigned short* __restrict__ X,
                const unsigned short* __restrict__ Wq,
                const unsigned short* __restrict__ Wk,
                const unsigned short* __restrict__ Wv,
                unsigned short* __restrict__ Qo,
                unsigned short* __restrict__ Ko,
                unsigned short* __restrict__ Vo)
{
    __shared__ unsigned short As[128 * 64];
    __shared__ unsigned short Bs[128 * 64];

    const int m0 = blockIdx.x * 128;
    const int by = blockIdx.y;
    const unsigned short* W = (by < 8) ? Wq : (by < 16) ? Wk : Wv;
    unsigned short*       O = (by < 8) ? Qo : (by < 16) ? Ko : Vo;
    const int n0   = (by & 7) * 128;
    const bool vsec = (by >= 16);
    const int tid  = threadIdx.x;
    const int lane = tid & 63;
    const int wv   = tid >> 6;
    const int wr   = (wv >> 1) * 64;
    const int wc   = (wv & 1) * 64;
    const int g    = lane >> 4;
    const int c    = lane & 15;

    f32x4 acc[4][4] = {};

    for (int k0 = 0; k0 < D_; k0 += 64) {
        #pragma unroll
        for (int i = 0; i < 4; ++i) {
            const int flat = i * 2048 + tid * 8;
            const int row = flat >> 6, col = flat & 63;
            gl_lds16(X + (size_t)(m0 + row) * D_ + k0 + col, As + flat);
            gl_lds16(W + (size_t)(n0 + row) * D_ + k0 + col, Bs + flat);
        }
        __syncthreads();
        #pragma unroll
        for (int kk = 0; kk < 64; kk += 32) {
            bf16x8 af[4], bg[4];
            #pragma unroll
            for (int mi = 0; mi < 4; ++mi)
                af[mi] = *(const bf16x8*)(As + (wr + mi * 16 + c) * 64 + kk + g * 8);
            #pragma unroll
            for (int ni = 0; ni < 4; ++ni)
                bg[ni] = *(const bf16x8*)(Bs + (wc + ni * 16 + c) * 64 + kk + g * 8);
            if (!vsec) {
                #pragma unroll
                for (int mi = 0; mi < 4; ++mi)
                    #pragma unroll
                    for (int ni = 0; ni < 4; ++ni)
                        acc[mi][ni] = mfma16(af[mi], bg[ni], acc[mi][ni]);
            } else {
                #pragma unroll
                for (int mi = 0; mi < 4; ++mi)
                    #pragma unroll
                    for (int ni = 0; ni < 4; ++ni)
                        acc[mi][ni] = mfma16(bg[ni], af[mi], acc[mi][ni]);
            }
        }
        __syncthreads();
    }

    if (!vsec) {
        #pragma unroll
        for (int mi = 0; mi < 4; ++mi)
            #pragma unroll
            for (int ni = 0; ni < 4; ++ni)
                #pragma unroll
                for (int r = 0; r < 4; ++r) {
                    const int m = m0 + wr + mi * 16 + g * 4 + r;
                    const int n = n0 + wc + ni * 16 + c;
                    const int b = m >> 11, t = m & (T_ - 1);
                    const int h = n >> 6,  hd = n & 63;
                    O[((size_t)((b << 4) + h) * T_ + t) * HD_ + hd] = f2bf(acc[mi][ni][r]);
                }
    } else {
        #pragma unroll
        for (int mi = 0; mi < 4; ++mi)
            #pragma unroll
            for (int ni = 0; ni < 4; ++ni)
                #pragma unroll
                for (int r = 0; r < 4; ++r) {
                    const int n = n0 + wc + ni * 16 + g * 4 + r;
                    const int m = m0 + wr + mi * 16 + c;
                    const int b = m >> 11, t = m & (T_ - 1);
                    const int h = n >> 6,  hd = n & 63;
                    O[((size_t)((b << 4) + h) * HD_ + hd) * T_ + t] = f2bf(acc[mi][ni][r]);
                }
    }
}

// ---------------------------------------------------------------------------
// Causal flash attention v13: 32x32 MFMA, 4 waves x 32 q-rows = 128 rows per
// block.  Grid (64 bh, 16 q-tiles) LPT.  Double-buffered LDS (identical
// staging + 3-bit XOR swizzle to r12), defer-max, setprio.
// ---------------------------------------------------------------------------
__global__ __launch_bounds__(256, 4)
void attn_kernel(const unsigned short* __restrict__ Q,
                 const unsigned short* __restrict__ K,
                 const unsigned short* __restrict__ VT,
                 unsigned short* __restrict__ Y)
{
    __shared__ unsigned short Ks[2][4096];   // K tiles, swizzled
    __shared__ unsigned short Vs[2][4096];   // V^T tiles, swizzled

    const int bh = blockIdx.x;          // fast axis -> XCD panel residency
    const int qt = 15 - blockIdx.y;     // LPT: heaviest q-tiles first
    const unsigned short* Qp  = Q  + (size_t)bh * T_ * HD_;
    const unsigned short* Kp  = K  + (size_t)bh * T_ * HD_;
    const unsigned short* VTp = VT + (size_t)bh * HD_ * T_;
    const int b = bh >> 4, h = bh & 15;

    const int tid  = threadIdx.x;
    const int lane = tid & 63;
    const int w    = tid >> 6;          // wave 0..3
    const int hi   = lane >> 5;         // lane half
    const int q31  = lane & 31;
    const float SC = 0.18033688011112042f;   // (1/sqrt(64)) * log2(e)

    const int qw = qt * 128 + w * 32;   // wave's q base (32 rows)
    const int nt = 2 * qt + 2;          // 64-key tiles (even)

    // Staging constants (identical to r12; 3-bit swizzle involution)
    int srow[2], scol[2];
    #pragma unroll
    for (int i = 0; i < 2; ++i) {
        const int L = (i * 256 + tid) * 16;
        srow[i] = L >> 7;                                   // 0..63
        scol[i] = (L & 127) ^ ((srow[i] & 7) << 4);         // pre-swizzled src col (bytes)
    }

    // Q as B-operand frags: col q = q31, k(d) = dstep*16 + hi*8 + j; pre-scaled
    bf16x8 qf[4];
    #pragma unroll
    for (int dstep = 0; dstep < 4; ++dstep) {
        bf16x8 t = *(const bf16x8*)(Qp + (size_t)(qw + q31) * HD_ + dstep * 16 + hi * 8);
        #pragma unroll
        for (int j = 0; j < 8; ++j)
            t[j] = (short)f2bf(bf2f((unsigned short)t[j]) * SC);
        qf[dstep] = t;
    }

    float m_l = -1e30f, l_l = 0.f;
    f32x16 o0 = {}, o1 = {};            // O^T: d-halves 0..31 / 32..63, col q
    const int swz = (lane & 7) << 4;    // read swizzle (read rows ≡ lane&7 mod 8)

    auto stage = [&](int buf, int tb) {
        #pragma unroll
        for (int i = 0; i < 2; ++i) {
            const int L = (i * 256 + tid) * 16;
            gl_lds16(Kp + (size_t)(tb + srow[i]) * HD_ + (scol[i] >> 1),
                     &Ks[buf][L >> 1]);
            gl_lds16(VTp + (size_t)srow[i] * T_ + tb + (scol[i] >> 1),
                     &Vs[buf][L >> 1]);
        }
    };

    auto compute = [&](const unsigned short* Kbuf, const unsigned short* Vbuf, int tb) {
        if (tb > qw + 31) return;       // wave fully masked
        const char* Kb = (const char*)Kbuf;
        const char* Vb = (const char*)Vbuf;

        __builtin_amdgcn_s_setprio(1);

        // ---- QK^T (swapped): s0 = keys tb..tb+31, s1 = tb+32..tb+63
        f32x16 s0 = {}, s1 = {};
        #pragma unroll
        for (int dstep = 0; dstep < 4; ++dstep) {
            const int col = (dstep * 32 + hi * 16) ^ swz;
            const bf16x8 kA = *(const bf16x8*)(Kb + q31 * 128 + col);
            const bf16x8 kB = *(const bf16x8*)(Kb + (32 + q31) * 128 + col);
            s0 = mfma32(kA, qf[dstep], s0);
            s1 = mfma32(kB, qf[dstep], s1);
        }

        // ---- causal mask (diagonal zone): key row = (r&3)+8*(r>>2)+4*hi
        if (tb + 63 > qw) {
            const int qq = qw + q31;
            #pragma unroll
            for (int r = 0; r < 16; ++r) {
                const int key = tb + (r & 3) + 8 * (r >> 2) + 4 * hi;
                s0[r] = (key      <= qq) ? s0[r] : -1e30f;
                s1[r] = (key + 32 <= qq) ? s1[r] : -1e30f;
            }
        }

        // ---- online softmax: per-lane 32 vals (one q) + 1 shuffle
        float pmax = s0[0];
        #pragma unroll
        for (int r = 1; r < 16; ++r) pmax = fmaxf(pmax, s0[r]);
        #pragma unroll
        for (int r = 0; r < 16; ++r) pmax = fmaxf(pmax, s1[r]);
        pmax = fmaxf(pmax, __shfl_xor(pmax, 32));

        const bool skip = __all(pmax - m_l <= 8.0f);
        float al = 1.f;
        if (!skip) {
            const float mn = fmaxf(m_l, pmax);
            al = exp2_fast(m_l - mn);
            m_l = mn;
        }

        float rs = 0.f;
        #pragma unroll
        for (int r = 0; r < 16; ++r) {
            const float e0 = exp2_fast(s0[r] - m_l);
            const float e1 = exp2_fast(s1[r] - m_l);
            s0[r] = e0; s1[r] = e1;
            rs += e0 + e1;
        }
        rs += __shfl_xor(rs, 32);
        l_l = l_l * al + rs;

        // ---- pack P into 4-reg groups (2 u32 each), exchange lane<->lane+32
        unsigned Glo0[4], Ghi0[4], Glo1[4], Ghi1[4];
        #pragma unroll
        for (int m = 0; m < 4; ++m) {
            Glo0[m] = (unsigned)f2bf(s0[4*m])   | ((unsigned)f2bf(s0[4*m+1]) << 16);
            Ghi0[m] = (unsigned)f2bf(s0[4*m+2]) | ((unsigned)f2bf(s0[4*m+3]) << 16);
            Glo1[m] = (unsigned)f2bf(s1[4*m])   | ((unsigned)f2bf(s1[4*m+1]) << 16);
            Ghi1[m] = (unsigned)f2bf(s1[4*m+2]) | ((unsigned)f2bf(s1[4*m+3]) << 16);
        }
        unsigned PGlo0[4], PGhi0[4], PGlo1[4], PGhi1[4];
        #pragma unroll
        for (int m = 0; m < 4; ++m) {
            PGlo0[m] = (unsigned)__shfl_xor((int)Glo0[m], 32);
            PGhi0[m] = (unsigned)__shfl_xor((int)Ghi0[m], 32);
            PGlo1[m] = (unsigned)__shfl_xor((int)Glo1[m], 32);
            PGhi1[m] = (unsigned)__shfl_xor((int)Ghi1[m], 32);
        }

        // ---- assemble PV B-frags: pf[ks], k = ks*16 + hi*8 + j
        // u01 = (q,lane-half 0)'s group m=2ksm+hi; u23 = (q,half 1)'s same group.
        bf16x8 pf[4];
        #pragma unroll
        for (int ks = 0; ks < 4; ++ks) {
            const int m0i = 2 * (ks & 1);
            const int m1i = m0i + 1;
            const unsigned gl0 = (ks < 2) ? Glo0[m0i] : Glo1[m0i];
            const unsigned gh0 = (ks < 2) ? Ghi0[m0i] : Ghi1[m0i];
            const unsigned gl1 = (ks < 2) ? Glo0[m1i] : Glo1[m1i];
            const unsigned gh1 = (ks < 2) ? Ghi0[m1i] : Ghi1[m1i];
            const unsigned pl0 = (ks < 2) ? PGlo0[m0i] : PGlo1[m0i];
            const unsigned ph0 = (ks < 2) ? PGhi0[m0i] : PGhi1[m0i];
            const unsigned pl1 = (ks < 2) ? PGlo0[m1i] : PGlo1[m1i];
            const unsigned ph1 = (ks < 2) ? PGhi0[m1i] : PGhi1[m1i];
            union { unsigned u[4]; bf16x8 v; } pp;
            pp.u[0] = hi ? pl1 : gl0;
            pp.u[1] = hi ? ph1 : gh0;
            pp.u[2] = hi ? gl1 : pl0;
            pp.u[3] = hi ? gh1 : ph0;
            pf[ks] = pp.v;
        }

        // ---- rescale (skipped when deferred) + PV
        if (!skip) {
            #pragma unroll
            for (int r = 0; r < 16; ++r) { o0[r] *= al; o1[r] *= al; }
        }
        #pragma unroll
        for (int ks = 0; ks < 4; ++ks) {
            const int col = (ks * 32 + hi * 16) ^ swz;
            const bf16x8 vA = *(const bf16x8*)(Vb + q31 * 128 + col);
            const bf16x8 vB = *(const bf16x8*)(Vb + (32 + q31) * 128 + col);
            o0 = mfma32(vA, pf[ks], o0);
            o1 = mfma32(vB, pf[ks], o1);
        }

        __builtin_amdgcn_s_setprio(0);
    };

    // 2x double-buffer pipeline (nt even)
    stage(0, 0);
    __syncthreads();
    for (int ti = 0; ti < nt; ti += 2) {
        stage(1, (ti + 1) << 6);
        compute(Ks[0], Vs[0], ti << 6);
        __syncthreads();
        if (ti + 2 < nt) stage(0, (ti + 2) << 6);
        compute(Ks[1], Vs[1], (ti + 1) << 6);
        __syncthreads();
    }

    // ---- epilogue: O[q = qw+q31][d = dhalf*32 + 8t + 4hi + e], uint2 stores
    const float li = 1.f / l_l;
    const size_t rowoff = (size_t)(b * T_ + qw + q31) * D_ + h * 64;
    #pragma unroll
    for (int t = 0; t < 4; ++t) {
        uint2 st0, st1;
        st0.x = (unsigned)f2bf(o0[4*t]   * li) | ((unsigned)f2bf(o0[4*t+1] * li) << 16);
        st0.y = (unsigned)f2bf(o0[4*t+2] * li) | ((unsigned)f2bf(o0[4*t+3] * li) << 16);
        st1.x = (unsigned)f2bf(o1[4*t]   * li) | ((unsigned)f2bf(o1[4*t+1] * li) << 16);
        st1.y = (unsigned)f2bf(o1[4*t+2] * li) | ((unsigned)f2bf(o1[4*t+3] * li) << 16);
        *(uint2*)(Y + rowoff      + 8 * t + 4 * hi) = st0;
        *(uint2*)(Y + rowoff + 32 + 8 * t + 4 * hi) = st1;
    }
}

// ---------------------------------------------------------------------------
// Output projection:  out = Y @ Wp^T + bp.  Y bf16[8192,1024]; out fp32.
// ---------------------------------------------------------------------------
__global__ __launch_bounds__(256, 2)
void proj_kernel(const unsigned short* __restrict__ Yin,
                 const unsigned short* __restrict__ Wp,
                 const float* __restrict__ bp,
                 float* __restrict__ Out)
{
    __shared__ unsigned short As[128 * 64];
    __shared__ unsigned short Bs[128 * 64];

    const int m0 = blockIdx.x * 128;
    const int n0 = blockIdx.y * 128;
    const int tid  = threadIdx.x;
    const int lane = tid & 63;
    const int wv   = tid >> 6;
    const int wr   = (wv >> 1) * 64;
    const int wc   = (wv & 1) * 64;
    const int g    = lane >> 4;
    const int c    = lane & 15;

    f32x4 acc[4][4] = {};

    for (int k0 = 0; k0 < D_; k0 += 64) {
        #pragma unroll
        for (int i = 0; i < 4; ++i) {
            const int flat = i * 2048 + tid * 8;
            const int row = flat >> 6, col = flat & 63;
            gl_lds16(Yin + (size_t)(m0 + row) * D_ + k0 + col, As + flat);
            gl_lds16(Wp  + (size_t)(n0 + row) * D_ + k0 + col, Bs + flat);
        }
        __syncthreads();
        #pragma unroll
        for (int kk = 0; kk < 64; kk += 32) {
            bf16x8 af[4], bg[4];
            #pragma unroll
            for (int mi = 0; mi < 4; ++mi)
                af[mi] = *(const bf16x8*)(As + (wr + mi * 16 + c) * 64 + kk + g * 8);
            #pragma unroll
            for (int ni = 0; ni < 4; ++ni)
                bg[ni] = *(const bf16x8*)(Bs + (wc + ni * 16 + c) * 64 + kk + g * 8);
            #pragma unroll
            for (int mi = 0; mi < 4; ++mi)
                #pragma unroll
                for (int ni = 0; ni < 4; ++ni)
                    acc[mi][ni] = mfma16(af[mi], bg[ni], acc[mi][ni]);
        }
        __syncthreads();
    }

    #pragma unroll
    for (int mi = 0; mi < 4; ++mi) {
        #pragma unroll
        for (int ni = 0; ni < 4; ++ni) {
            const int n = n0 + wc + ni * 16 + c;
            const float bb = bp[n];
            #pragma unroll
            for (int r = 0; r < 4; ++r) {
                const int m = m0 + wr + mi * 16 + g * 4 + r;
                Out[(size_t)m * D_ + n] = acc[mi][ni][r] + bb;
            }
        }
    }
}

// ---------------------------------------------------------------------------
extern "C" void kernel_launch(void* const* d_in, const int* in_sizes, int n_in,
                              void* d_out, int out_size, void* d_ws, size_t ws_size,
                              hipStream_t stream) {
    const float* x  = (const float*)d_in[0];
    const float* Wq = (const float*)d_in[1];
    const float* Wk = (const float*)d_in[2];
    const float* Wv = (const float*)d_in[3];
    const float* Wp = (const float*)d_in[4];
    const float* bp = (const float*)d_in[5];
    float* out = (float*)d_out;

    const size_t SZ  = (size_t)M_ * D_;      // 8388608
    const size_t WSZ = (size_t)D_ * D_;      // 1048576
    unsigned short* ws = (unsigned short*)d_ws;
    unsigned short* XB  = ws;                 // also Y after qkv
    unsigned short* WQB = XB  + SZ;
    unsigned short* WKB = WQB + WSZ;
    unsigned short* WVB = WKB + WSZ;
    unsigned short* WPB = WVB + WSZ;
    unsigned short* Qw  = WPB + WSZ;
    unsigned short* Kw  = Qw + SZ;
    unsigned short* Vw  = Kw + SZ;            // V^T [B,H,HD,T]
    unsigned short* Yw  = XB;                 // overlay: x_bf16 dead after qkv

    dim3 blk(256);
    cvt_all_kernel<<<dim3(12288), blk, 0, stream>>>(x, Wq, Wk, Wv, Wp, ws);

    qkv_kernel <<<dim3(M_ / 128, 24), blk, 0, stream>>>(XB, WQB, WKB, WVB, Qw, Kw, Vw);
    attn_kernel<<<dim3(B_ * H_, 16), blk, 0, stream>>>(Qw, Kw, Vw, Yw);
    proj_kernel<<<dim3(M_ / 128, D_ / 128), blk, 0, stream>>>(Yw, WPB, bp, out);
}